// Round 8
// baseline (561.264 us; speedup 1.0000x reference)
//
#include <hip/hip_runtime.h>
#include <hip/hip_bf16.h>

// QuantizedLinear: out[8192,4096] = x[8192,4096] @ W^T + bias
//   W[n,k] = codebooks[codes[n, k/8]][k%8] * scales[n]  (NCB=1; scale in epilogue)
// Round-8 GEMM: 256x256, BK=64, 8 waves (2Mx4N), mfma_f32_32x32x16_bf16.
// LDS layout stores each slot as [ks][half][row] 16B-chunk sub-blocks so every
// wave-wide ds_read batch is a dense contiguous 512B x2 run -> conflict-free
// with NO swizzle, and global_load_lds staging maps linearly (chunk = (i*8+w)*64+lane).
// 4 uniform windows/group: {stage i, read ks+1, LGKM(6), 8 MFMA, VMC(4), BAR}.
#define M_DIM 8192
#define N_DIM 4096
#define K_DIM 4096
#define NOG 4096
#define NIG 512

typedef __bf16 bf16x8 __attribute__((ext_vector_type(8)));
typedef float f32x16 __attribute__((ext_vector_type(16)));
typedef short short8 __attribute__((ext_vector_type(8)));

typedef const __attribute__((address_space(1))) void* as1_cvoid_p;
typedef __attribute__((address_space(3))) void* as3_void_p;

__device__ __forceinline__ unsigned short f2bf(float f) {
  union { float f; unsigned u; } c; c.f = f;
  unsigned u = c.u;
  return (unsigned short)((u + 0x7fffu + ((u >> 16) & 1u)) >> 16);
}

// ---- Kernel 1: x f32 -> bf16
__global__ __launch_bounds__(256) void cvt_x_kernel(const float* __restrict__ x,
                                                    unsigned short* __restrict__ xb,
                                                    int n8) {
  int i = blockIdx.x * blockDim.x + threadIdx.x;
  int stride = gridDim.x * blockDim.x;
  for (; i < n8; i += stride) {
    const float4* p = (const float4*)(x) + (size_t)i * 2;
    float4 a = p[0], b = p[1];
    short8 o;
    o[0] = (short)f2bf(a.x); o[1] = (short)f2bf(a.y);
    o[2] = (short)f2bf(a.z); o[3] = (short)f2bf(a.w);
    o[4] = (short)f2bf(b.x); o[5] = (short)f2bf(b.y);
    o[6] = (short)f2bf(b.z); o[7] = (short)f2bf(b.w);
    ((short8*)xb)[i] = o;
  }
}

// ---- Kernel 2: gather-dequant -> bf16 W [N][K]
__global__ __launch_bounds__(256) void dequant_kernel(const int* __restrict__ codes,
                                                      const float* __restrict__ cb,
                                                      unsigned short* __restrict__ wb) {
  int idx = blockIdx.x * blockDim.x + threadIdx.x;
  int code = codes[idx];
  const float4* p = (const float4*)(cb + (size_t)code * 8);
  float4 a = p[0], b = p[1];
  short8 o;
  o[0] = (short)f2bf(a.x); o[1] = (short)f2bf(a.y);
  o[2] = (short)f2bf(a.z); o[3] = (short)f2bf(a.w);
  o[4] = (short)f2bf(b.x); o[5] = (short)f2bf(b.y);
  o[6] = (short)f2bf(b.z); o[7] = (short)f2bf(b.w);
  ((short8*)wb)[idx] = o;
}

// ---- Kernel 3 ----------------------------------------------------------
// LDS per slot s: A at s*32768, B at 65536+s*32768; within: chunk index
// c = ks*512 + half*256 + row, byte = c*16. Stage instr i per wave covers
// chunks (i*8+w)*64 .. +63 -> ks=i, half=w>>2, rows (w&3)*64+lane (global
// source: 64 consecutive rows x 16B at koff i*16+(w>>2)*8). Reads for k-step
// ks: lane q=l>>5, addr = ks*8192 + q*4096 + row*16 (dense 512B runs).

#define BAR() __builtin_amdgcn_s_barrier()
#define SB() __builtin_amdgcn_sched_barrier(0)
#define PRIO1() __builtin_amdgcn_s_setprio(1)
#define PRIO0() __builtin_amdgcn_s_setprio(0)
#define LGKM(N_) asm volatile("s_waitcnt lgkmcnt(" #N_ ")" ::: "memory")
#define VMC(N_) asm volatile("s_waitcnt vmcnt(" #N_ ")" ::: "memory")

// stage instr i_ of A (isB_=0) or B (isB_=1) for tile in slot_, K-base kt_
#define STAGE_I(G_, isB_, slot_, i_, kt_) do { \
  const unsigned short* src_ = (G_) + (size_t)(srow0 + l) * 4096 + (unsigned)((kt_) + (i_) * 16 + shalf8); \
  __builtin_amdgcn_global_load_lds((as1_cvoid_p)src_, \
    (as3_void_p)(smem + (isB_) * 65536 + (slot_) * 32768 + ((i_) * 8 + w) * 1024), 16, 0, 0); \
} while (0)

// A fragment reads for k-step ks_: 4 x b128
#define LDA32(dst_, ks_, slot_) \
  _Pragma("unroll") for (int mf_ = 0; mf_ < 4; ++mf_) \
    dst_[mf_] = *(const bf16x8*)(smem + (slot_) * 32768 + (ks_) * 8192 + aRd0 + mf_ * 512);

// B fragment reads for k-step ks_: 2 x b128
#define LDB32(dst_, ks_, slot_) \
  _Pragma("unroll") for (int nf_ = 0; nf_ < 2; ++nf_) \
    dst_[nf_] = *(const bf16x8*)(smem + 65536 + (slot_) * 32768 + (ks_) * 8192 + bRd0 + nf_ * 512);

// 8 x mfma_32x32x16
#define MFMA8(af_, bf_) \
  _Pragma("unroll") for (int mf_ = 0; mf_ < 4; ++mf_) \
  _Pragma("unroll") for (int nf_ = 0; nf_ < 2; ++nf_) \
    acc[mf_][nf_] = __builtin_amdgcn_mfma_f32_32x32x16_bf16(af_[mf_], bf_[nf_], acc[mf_][nf_], 0, 0, 0);

// MODE 2 = steady (stage tile t+1); MODE 0 = last group (no stage)
#define GROUP32(S_, MODE_, KT_) do { \
  /* W0: stage i0(t+1); read ks1; MFMA ks0 */ \
  if ((MODE_) == 2) { STAGE_I(Ag, 0, (S_) ^ 1, 0, (KT_) + 64); STAGE_I(Bg, 1, (S_) ^ 1, 0, (KT_) + 64); } \
  LDA32(afB, 1, S_); LDB32(bfB, 1, S_); SB(); \
  LGKM(6); SB(); PRIO1(); MFMA8(afA, bfA); PRIO0(); SB(); \
  if ((MODE_) == 2) { VMC(4); } else { VMC(2); } \
  BAR(); \
  /* W1: stage i1; read ks2; MFMA ks1 */ \
  if ((MODE_) == 2) { STAGE_I(Ag, 0, (S_) ^ 1, 1, (KT_) + 64); STAGE_I(Bg, 1, (S_) ^ 1, 1, (KT_) + 64); } \
  LDA32(afA, 2, S_); LDB32(bfA, 2, S_); SB(); \
  LGKM(6); SB(); PRIO1(); MFMA8(afB, bfB); PRIO0(); SB(); \
  if ((MODE_) == 2) { VMC(4); } else { VMC(0); } \
  BAR(); \
  /* W2: stage i2; read ks3; MFMA ks2 */ \
  if ((MODE_) == 2) { STAGE_I(Ag, 0, (S_) ^ 1, 2, (KT_) + 64); STAGE_I(Bg, 1, (S_) ^ 1, 2, (KT_) + 64); } \
  LDA32(afB, 3, S_); LDB32(bfB, 3, S_); SB(); \
  LGKM(6); SB(); PRIO1(); MFMA8(afA, bfA); PRIO0(); SB(); \
  if ((MODE_) == 2) { VMC(4); } \
  BAR(); \
  /* W3: stage i3; read ks0(t+1) from S^1; MFMA ks3 */ \
  if ((MODE_) == 2) { STAGE_I(Ag, 0, (S_) ^ 1, 3, (KT_) + 64); STAGE_I(Bg, 1, (S_) ^ 1, 3, (KT_) + 64); } \
  if ((MODE_) == 2) { LDA32(afA, 0, (S_) ^ 1); LDB32(bfA, 0, (S_) ^ 1); } \
  SB(); \
  if ((MODE_) == 2) { LGKM(6); } else { LGKM(0); } \
  SB(); PRIO1(); MFMA8(afB, bfB); PRIO0(); SB(); \
  if ((MODE_) == 2) { VMC(4); } \
  BAR(); \
} while (0)

__global__ __launch_bounds__(512) void gemm8_kernel(
    const unsigned short* __restrict__ A,   // bf16 [M][K]
    const unsigned short* __restrict__ B,   // bf16 [N][K]
    const float* __restrict__ scales,
    const float* __restrict__ bias,
    float* __restrict__ C) {
  extern __shared__ char smem[];  // 131072 B

  // grid 512 = 32 bm x 16 bn; bijective XCD swizzle (512 % 8 == 0)
  const int bid = blockIdx.x;
  const int swz = (bid & 7) * 64 + (bid >> 3);
  const int bm = swz >> 4;
  const int bn = swz & 15;

  const int tid = threadIdx.x;
  const int w = tid >> 6;
  const int l = tid & 63;
  const int wr = w >> 2;    // 0..1 (M half)
  const int wcol = w & 3;   // 0..3 (N quarter)

  // staging constants
  const int srow0 = (w & 3) * 64;
  const int shalf8 = ((w >> 2) & 1) * 8;

  const unsigned short* Ag = A + (size_t)bm * 256 * 4096;
  const unsigned short* Bg = B + (size_t)bn * 256 * 4096;

  // fragment read bases: q=l>>5 selects k-half, row*16 within sub-block
  const int aRd0 = ((l >> 5) * 4096) + (wr * 128 + (l & 31)) * 16;
  const int bRd0 = ((l >> 5) * 4096) + (wcol * 64 + (l & 31)) * 16;

  f32x16 acc[4][2];
#pragma unroll
  for (int mf = 0; mf < 4; ++mf)
#pragma unroll
    for (int nf = 0; nf < 2; ++nf)
#pragma unroll
      for (int r = 0; r < 16; ++r) acc[mf][nf][r] = 0.f;

  bf16x8 afA[4], afB[4], bfA[2], bfB[2];

  // ---- prologue: stage tile0 (i order 0,0,1,1,2,2,3,3) -> slot0; VMC(4); prime ks0
  STAGE_I(Ag, 0, 0, 0, 0); STAGE_I(Bg, 1, 0, 0, 0);
  STAGE_I(Ag, 0, 0, 1, 0); STAGE_I(Bg, 1, 0, 1, 0);
  STAGE_I(Ag, 0, 0, 2, 0); STAGE_I(Bg, 1, 0, 2, 0);
  STAGE_I(Ag, 0, 0, 3, 0); STAGE_I(Bg, 1, 0, 3, 0);
  VMC(4);   // ks0,ks1 resident; in flight [SA2,SB2,SA3,SB3] = steady invariant
  BAR();
  LDA32(afA, 0, 0); LDB32(bfA, 0, 0); SB();   // ks0 reads (6 lgkm in flight)

  // ---- main loop: 64 K-tiles, slot = t&1
  int kt = 0;
  for (int j = 0; j < 31; ++j) {
    GROUP32(0, 2, kt);
    GROUP32(1, 2, kt + 64);
    kt += 128;
  }
  GROUP32(0, 2, 3968);   // t=62 (stages tile 63 -> slot 1)
  GROUP32(1, 0, 4032);   // t=63 (no stage)

  // ---- epilogue: C/D 32x32 layout col=l&31, row=(reg&3)+8*(reg>>2)+4*(l>>5)
  const int r0 = bm * 256 + wr * 128 + 4 * (l >> 5);
  const int c0 = bn * 256 + wcol * 64 + (l & 31);
#pragma unroll
  for (int nf = 0; nf < 2; ++nf) {
    const int col = c0 + nf * 32;
    const float s = scales[col];
    const float bv = bias[col];
#pragma unroll
    for (int mf = 0; mf < 4; ++mf) {
      f32x16 v = acc[mf][nf];
      const int rb = r0 + mf * 32;
#pragma unroll
      for (int r = 0; r < 16; ++r)
        C[(size_t)(rb + (r & 3) + 8 * (r >> 2)) * 4096 + col] = v[r] * s + bv;
    }
  }
}

extern "C" void kernel_launch(void* const* d_in, const int* in_sizes, int n_in,
                              void* d_out, int out_size, void* d_ws, size_t ws_size,
                              hipStream_t stream) {
  const float* x = (const float*)d_in[0];
  const int* codes = (const int*)d_in[1];
  const float* cb = (const float*)d_in[2];
  const float* scales = (const float*)d_in[3];
  const float* bias = (const float*)d_in[4];
  float* out = (float*)d_out;

  unsigned short* xb = (unsigned short*)d_ws;
  unsigned short* wb = (unsigned short*)((char*)d_ws + (size_t)M_DIM * K_DIM * 2);

  hipFuncSetAttribute((const void*)gemm8_kernel,
                      hipFuncAttributeMaxDynamicSharedMemorySize, 131072);

  cvt_x_kernel<<<4096, 256, 0, stream>>>(x, xb, (M_DIM * K_DIM) / 8);
  dequant_kernel<<<(NOG * NIG) / 256, 256, 0, stream>>>(codes, cb, wb);
  gemm8_kernel<<<dim3((M_DIM / 256) * (N_DIM / 256)), 512, 131072, stream>>>(
      xb, wb, scales, bias, out);
}

// Round 10
// 255.162 us; speedup vs baseline: 2.1996x; 2.1996x over previous
//
#include <hip/hip_runtime.h>
#include <hip/hip_bf16.h>

// QuantizedLinear: out[8192,4096] = x[8192,4096] @ W^T + bias
//   W[n,k] = codebooks[codes[n, k/8]][k%8] * scales[n]  (NCB=1; scale in epilogue)
// Round-10: GEMM = r4 kernel verbatim (best passing: 215us, 58.5% MfmaUtil).
// cvt_x + dequant merged into one launch (block-range split) to cut a launch gap.
// r9 lesson: staged-LDS reads need (all waves' vmcnt) -> BARRIER -> read; r4's
// schedule satisfies this (AH(t) via VMC(8)@W0+BAR; AL/BL/BH(t+1) via VMC(6)@W2+BAR).
#define M_DIM 8192
#define N_DIM 4096
#define K_DIM 4096
#define NOG 4096
#define NIG 512

typedef __bf16 bf16x8 __attribute__((ext_vector_type(8)));
typedef float f32x4 __attribute__((ext_vector_type(4)));
typedef short short8 __attribute__((ext_vector_type(8)));

typedef const __attribute__((address_space(1))) void* as1_cvoid_p;
typedef __attribute__((address_space(3))) void* as3_void_p;

__device__ __forceinline__ unsigned short f2bf(float f) {
  union { float f; unsigned u; } c; c.f = f;
  unsigned u = c.u;
  return (unsigned short)((u + 0x7fffu + ((u >> 16) & 1u)) >> 16);
}

// ---- Kernel 1: merged prep — blocks [0,4096): x f32->bf16; [4096,12288): dequant
__global__ __launch_bounds__(256) void prep_kernel(const float* __restrict__ x,
                                                   unsigned short* __restrict__ xb,
                                                   const int* __restrict__ codes,
                                                   const float* __restrict__ cb,
                                                   unsigned short* __restrict__ wb) {
  if (blockIdx.x < 4096) {
    const int n8 = (M_DIM * K_DIM) / 8;
    int i = blockIdx.x * 256 + threadIdx.x;
    const int stride = 4096 * 256;
    for (; i < n8; i += stride) {
      const float4* p = (const float4*)(x) + (size_t)i * 2;
      float4 a = p[0], b = p[1];
      short8 o;
      o[0] = (short)f2bf(a.x); o[1] = (short)f2bf(a.y);
      o[2] = (short)f2bf(a.z); o[3] = (short)f2bf(a.w);
      o[4] = (short)f2bf(b.x); o[5] = (short)f2bf(b.y);
      o[6] = (short)f2bf(b.z); o[7] = (short)f2bf(b.w);
      ((short8*)xb)[i] = o;
    }
  } else {
    int idx = (blockIdx.x - 4096) * 256 + threadIdx.x;   // n*NIG + ig
    int code = codes[idx];
    const float4* p = (const float4*)(cb + (size_t)code * 8);
    float4 a = p[0], b = p[1];
    short8 o;
    o[0] = (short)f2bf(a.x); o[1] = (short)f2bf(a.y);
    o[2] = (short)f2bf(a.z); o[3] = (short)f2bf(a.w);
    o[4] = (short)f2bf(b.x); o[5] = (short)f2bf(b.y);
    o[6] = (short)f2bf(b.z); o[7] = (short)f2bf(b.w);
    ((short8*)wb)[idx] = o;
  }
}

// ---- Kernel 2: 256x256 GEMM, BK=64, 8 waves (2Mx4N), 128 KiB LDS (2 slots),
// st_16x32 swizzle (r4 verbatim). Stages: W0:AH(t+1)->s^1  W1:AL(t+2)->s
// W2:BL(t+2)->s  W3:BH(t+2)->s. Reads one window early: W1-end aH(t);
// W3-end aL/bL/bH(t+1). Waits: VMC(8)@W0-end, VMC(6)@W2-end; barriers W0/W1/W2.

#define BAR() __builtin_amdgcn_s_barrier()
#define SB() __builtin_amdgcn_sched_barrier(0)
#define PRIO1() __builtin_amdgcn_s_setprio(1)
#define PRIO0() __builtin_amdgcn_s_setprio(0)
#define LGKM(N_) asm volatile("s_waitcnt lgkmcnt(" #N_ ")" ::: "memory")
#define VMC(N_) asm volatile("s_waitcnt vmcnt(" #N_ ")" ::: "memory")

#define STAGE_A(slot_, h_, kt_) do { \
  _Pragma("unroll") for (int i_ = 0; i_ < 2; ++i_) { \
    const unsigned short* src_ = Ag + (size_t)(sa_roff[i_] + (h_) * 64) * 4096 + (unsigned)((kt_) + sa_koff[i_]); \
    __builtin_amdgcn_global_load_lds((as1_cvoid_p)src_, \
      (as3_void_p)(smem + (slot_) * 32768 + sa_lds[i_] + (h_) * 4096), 16, 0, 0); \
  } } while (0)

#define STAGE_B(slot_, h_, kt_) do { \
  _Pragma("unroll") for (int i_ = 0; i_ < 2; ++i_) { \
    const unsigned short* src_ = Bg + (size_t)(sb_roff[i_] + (h_) * 32) * 4096 + (unsigned)((kt_) + sb_koff[i_]); \
    __builtin_amdgcn_global_load_lds((as1_cvoid_p)src_, \
      (as3_void_p)(smem + 65536 + (slot_) * 32768 + sb_lds[i_] + (h_) * 2048), 16, 0, 0); \
  } } while (0)

#define LDA_Q(q_, ma_, slot_) \
  _Pragma("unroll") for (int j_ = 0; j_ < 2; ++j_) \
  _Pragma("unroll") for (int kk_ = 0; kk_ < 2; ++kk_) \
    af[(q_) * 2 + j_][kk_] = *(const bf16x8*)(smem + (slot_) * 32768 + aRd + ((ma_) * 4 + (q_) * 2 + j_) * 1024 + kk_ * 16384);

#define LDB(n0_, dst_, slot_) \
  _Pragma("unroll") for (int n_ = 0; n_ < 2; ++n_) \
  _Pragma("unroll") for (int kk_ = 0; kk_ < 2; ++kk_) \
    dst_[n_][kk_] = *(const bf16x8*)(smem + (slot_) * 32768 + bRd + ((n0_) + n_) * 1024 + kk_ * 16384);

#define MM_Q(base_, q_, nb_, bfr_) \
  _Pragma("unroll") for (int j_ = 0; j_ < 2; ++j_) \
  _Pragma("unroll") for (int n_ = 0; n_ < 2; ++n_) \
  _Pragma("unroll") for (int kk_ = 0; kk_ < 2; ++kk_) \
    acc[(base_) + (q_) * 2 + j_][(nb_) + n_] = __builtin_amdgcn_mfma_f32_16x16x32_bf16( \
        af[(q_) * 2 + j_][kk_], bfr_[n_][kk_], acc[(base_) + (q_) * 2 + j_][(nb_) + n_], 0, 0, 0);

#define REFILL_NEXT(slotn_) do { \
  LDA_Q(0, 0, slotn_); SB(); LDB(0, bf0, slotn_); SB(); \
  LDA_Q(1, 0, slotn_); SB(); LDB(2, bf1, slotn_); SB(); \
} while (0)

// MODE: 2=steady, 1=g=62 (stage AH only; VMC {8,-,2}), 0=g=63 (VMC(0)@W0; no refill)
#define GROUP(SLOT_, MODE_, KT_) do { \
  /* W0: MFMA aL x bL; stage AH(t+1) */ \
  if ((MODE_) >= 1) STAGE_A((SLOT_) ^ 1, 1, (KT_) + 64); \
  LGKM(8); SB(); PRIO1(); MM_Q(0, 0, 0, bf0); \
  LGKM(4); SB(); MM_Q(0, 1, 0, bf0); PRIO0(); \
  if ((MODE_) >= 1) { VMC(8); } else { VMC(0); } \
  BAR(); \
  /* W1: MFMA aL x bH; stage AL(t+2); refill af <- aH(t) at end */ \
  if ((MODE_) == 2) STAGE_A(SLOT_, 0, (KT_) + 128); \
  LGKM(0); SB(); PRIO1(); MM_Q(0, 0, 2, bf1); MM_Q(0, 1, 2, bf1); PRIO0(); \
  LDA_Q(0, 1, SLOT_); SB(); LDA_Q(1, 1, SLOT_); SB(); \
  BAR(); \
  /* W2: MFMA aH x bL; stage BL(t+2) */ \
  if ((MODE_) == 2) STAGE_B(SLOT_, 0, (KT_) + 128); \
  LGKM(4); SB(); PRIO1(); MM_Q(4, 0, 0, bf0); \
  LGKM(0); SB(); MM_Q(4, 1, 0, bf0); PRIO0(); \
  if ((MODE_) == 2) { VMC(6); } else if ((MODE_) == 1) { VMC(2); } \
  BAR(); \
  /* W3: MFMA aH x bH; stage BH(t+2); refill next-tile frags at end */ \
  if ((MODE_) == 2) STAGE_B(SLOT_, 1, (KT_) + 128); \
  PRIO1(); MM_Q(4, 0, 2, bf1); MM_Q(4, 1, 2, bf1); PRIO0(); \
  if ((MODE_) >= 1) REFILL_NEXT((SLOT_) ^ 1); \
} while (0)

__global__ __launch_bounds__(512) void gemm8_kernel(
    const unsigned short* __restrict__ A,   // bf16 [M][K]
    const unsigned short* __restrict__ B,   // bf16 [N][K]
    const float* __restrict__ scales,
    const float* __restrict__ bias,
    float* __restrict__ C) {
  extern __shared__ char smem[];  // 131072 B

  // grid 512 = 32 bm x 16 bn; bijective XCD swizzle (512 % 8 == 0)
  const int bid = blockIdx.x;
  const int swz = (bid & 7) * 64 + (bid >> 3);
  const int bm = swz >> 4;
  const int bn = swz & 15;

  const int tid = threadIdx.x;
  const int w = tid >> 6;
  const int l = tid & 63;
  const int wr = w >> 2;    // 0..1
  const int wcol = w & 3;   // 0..3

  // ---- staging constants (linear LDS dest, inverse-swizzled global source)
  const int llog = l ^ (((l >> 5) & 1) << 1);
  int sa_roff[2], sa_koff[2], sa_lds[2];
  int sb_roff[2], sb_koff[2], sb_lds[2];
#pragma unroll
  for (int i = 0; i < 2; ++i) {
    int u = w * 2 + i;
    int panel = u >> 3;
    int rbA = (u >> 2) & 1, chA = u & 3;
    sa_roff[i] = rbA * 128 + chA * 16 + (llog >> 2);
    sa_koff[i] = panel * 32 + (llog & 3) * 8;
    sa_lds[i] = panel * 16384 + rbA * 8192 + chA * 1024;
    int bb = (u >> 1) & 3, hk = u & 1;
    sb_roff[i] = bb * 64 + hk * 16 + (llog >> 2);
    sb_koff[i] = panel * 32 + (llog & 3) * 8;
    sb_lds[i] = panel * 16384 + bb * 4096 + hk * 1024;
  }

  const unsigned short* Ag = A + (size_t)bm * 256 * 4096;
  const unsigned short* Bg = B + (size_t)bn * 256 * 4096;

  // ---- fragment read base addresses (swizzled)
  const int xr = ((l >> 4) * 16) ^ (((l >> 3) & 1) << 5);
  const int aRd = (wr * 128 + (l & 15)) * 64 + xr;
  const int bRd = 65536 + (wcol * 64 + (l & 15)) * 64 + xr;

  f32x4 acc[8][4];
#pragma unroll
  for (int m = 0; m < 8; ++m)
#pragma unroll
    for (int n = 0; n < 4; ++n) acc[m][n] = (f32x4){0.f, 0.f, 0.f, 0.f};

  bf16x8 af[4][2], bf0[2][2], bf1[2][2];

  // ---- prologue: stage AL0,BL0,BH0 | AH0 | AL1,BL1,BH1; drain first 3; prime reads
  STAGE_A(0, 0, 0); STAGE_B(0, 0, 0); STAGE_B(0, 1, 0);
  STAGE_A(0, 1, 0);
  STAGE_A(1, 0, 64); STAGE_B(1, 0, 64); STAGE_B(1, 1, 64);
  VMC(8);   // 14 outstanding -> keep 8 newest {AH0, AL1, BL1, BH1}
  BAR();
  REFILL_NEXT(0);   // aL0 q1, bL0, aL0 q2, bH0 (16 reads in flight, steady invariant)

  // ---- main loop: 64 K-tiles; groups 0..61 steady, 62 penult, 63 last
  int kt = 0;
  for (int j = 0; j < 31; ++j) {
    GROUP(0, 2, kt);
    GROUP(1, 2, kt + 64);
    kt += 128;
  }
  GROUP(0, 1, kt);        // g=62: stages AH(63) only
  GROUP(1, 0, kt + 64);   // g=63

  // ---- epilogue: scale + bias, fp32 store
  const int row0 = bm * 256 + wr * 128 + ((l >> 4) << 2);
  const int col0 = bn * 256 + wcol * 64 + (l & 15);
#pragma unroll
  for (int n = 0; n < 4; ++n) {
    const int col = col0 + n * 16;
    const float s = scales[col];
    const float bv = bias[col];
#pragma unroll
    for (int m = 0; m < 8; ++m) {
      f32x4 v = acc[m][n];
      const int r = row0 + m * 16;
#pragma unroll
      for (int j = 0; j < 4; ++j)
        C[(size_t)(r + j) * 4096 + col] = v[j] * s + bv;
    }
  }
}

extern "C" void kernel_launch(void* const* d_in, const int* in_sizes, int n_in,
                              void* d_out, int out_size, void* d_ws, size_t ws_size,
                              hipStream_t stream) {
  const float* x = (const float*)d_in[0];
  const int* codes = (const int*)d_in[1];
  const float* cb = (const float*)d_in[2];
  const float* scales = (const float*)d_in[3];
  const float* bias = (const float*)d_in[4];
  float* out = (float*)d_out;

  unsigned short* xb = (unsigned short*)d_ws;
  unsigned short* wb = (unsigned short*)((char*)d_ws + (size_t)M_DIM * K_DIM * 2);

  hipFuncSetAttribute((const void*)gemm8_kernel,
                      hipFuncAttributeMaxDynamicSharedMemorySize, 131072);

  prep_kernel<<<4096 + (NOG * NIG) / 256, 256, 0, stream>>>(x, xb, codes, cb, wb);
  gemm8_kernel<<<dim3((M_DIM / 256) * (N_DIM / 256)), 512, 131072, stream>>>(
      xb, wb, scales, bias, out);
}